// Round 4
// baseline (307.531 us; speedup 1.0000x reference)
//
#include <hip/hip_runtime.h>
#include <hip/hip_bf16.h>

#define BB 8
#define SS 2048
#define NN 1024
#define MT (BB*SS)   // 16384
#define NKC 16       // key tiles of 128; each wave owns a 64-key strip -> 32 partials/row
#define NPC 32       // partial chunks per row (NKC * 2 wave-columns)

typedef __attribute__((ext_vector_type(8))) short bf16x8;
typedef __attribute__((ext_vector_type(4))) float f32x4;
typedef unsigned short u16;
typedef unsigned int u32;

__device__ __forceinline__ u16 f2bf(float f) {
  u32 u = __float_as_uint(f);
  u += 0x7fff + ((u >> 16) & 1);
  return (u16)(u >> 16);
}
__device__ __forceinline__ float bf2f(u16 h) {
  return __uint_as_float(((u32)h) << 16);
}

typedef __attribute__((address_space(1))) void GV;
typedef __attribute__((address_space(3))) void LV;
__device__ __forceinline__ void cp16(const void* g, void* l) {
  __builtin_amdgcn_global_load_lds((GV*)g, (LV*)l, 16, 0, 0);
}

// ---------------- prep: cast outer -> bf16, rowsum -> r (1 wave per row) -----
__global__ __launch_bounds__(256) void prep_x_kernel(const float* __restrict__ outer,
                                                     u16* __restrict__ Xb,
                                                     float* __restrict__ r) {
  int w = threadIdx.x >> 6, lane = threadIdx.x & 63;
  int row = blockIdx.x * 4 + w;
  const float4* src = (const float4*)(outer + (size_t)row * NN);
  ushort4* dst = (ushort4*)(Xb + (size_t)row * NN);
  float s = 0.f;
#pragma unroll
  for (int u = 0; u < 4; u++) {
    int idx = lane + u * 64;
    float4 v = src[idx];
    ushort4 o;
    o.x = f2bf(v.x); o.y = f2bf(v.y); o.z = f2bf(v.z); o.w = f2bf(v.w);
    dst[idx] = o;
    s += (v.x + v.y) + (v.z + v.w);
  }
#pragma unroll
  for (int off = 1; off < 64; off <<= 1) s += __shfl_xor(s, off);
  if (lane == 0) r[row] = s;
}

// ---------------- prep: cast weights -> bf16 (rows 0..1023 = Wq, 1024.. = Wk) --
__global__ __launch_bounds__(256) void prep_w_kernel(const float* __restrict__ Wq,
                                                     const float* __restrict__ Wk,
                                                     const float* __restrict__ bq,
                                                     const float* __restrict__ bk,
                                                     u16* __restrict__ Wb,
                                                     float* __restrict__ bb) {
  int idx = blockIdx.x * 256 + threadIdx.x;   // 0 .. 524287 (x4 elems)
  int e = idx * 4;
  int rowm = e >> 10;
  int col = e & 1023;
  const float* srcp = (rowm < NN) ? (Wq + (size_t)rowm * NN + col)
                                  : (Wk + (size_t)(rowm - NN) * NN + col);
  float4 v = *(const float4*)srcp;
  ushort4 o; o.x = f2bf(v.x); o.y = f2bf(v.y); o.z = f2bf(v.z); o.w = f2bf(v.w);
  *(ushort4*)(Wb + (size_t)e) = o;
  if (idx < 2 * NN) bb[idx] = (idx < NN) ? bq[idx] : bk[idx - NN];
}

// ---------------- stage 1 GEMM: C[row][m] = sigmoid(X.Wb^T + bb) - 0.5 (bf16) --
// m97 structure: 4 waves 2x2, 64x64 per wave, BK=32: 16 MFMA / 8 ds_read_b128
__global__ __launch_bounds__(256, 3) void gemm1_kernel(const u16* __restrict__ X,
                                                       const u16* __restrict__ W,
                                                       const float* __restrict__ bb,
                                                       u16* __restrict__ C) {
  __shared__ u16 lA[128 * 32];
  __shared__ u16 lB[128 * 32];
  int tn = blockIdx.x;   // 16 (fast -> share X-tile in L2)
  int tm = blockIdx.y;   // 128
  int tid = threadIdx.x;
  int w = tid >> 6, lane = tid & 63;
  int wr = w >> 1, wc = w & 1;
  int srow = tid >> 2;
  int scol = (tid & 3) * 8;
  const u16* gA = X + (size_t)(tm * 128 + srow) * NN + scol;
  const u16* gB = W + (size_t)(tn * 128 + srow) * NN + scol;
  u16* dA = &lA[srow * 32 + scol];
  u16* dB = &lB[srow * 32 + scol];
  int quad = lane >> 4;
  const u16* pa0 = &lA[(wr * 64 + (lane & 15)) * 32 + quad * 8];
  const u16* pb0 = &lB[(wc * 64 + (lane & 15)) * 32 + quad * 8];
  f32x4 acc[4][4] = {};
  for (int kk = 0; kk < NN; kk += 32) {
    cp16(gA, dA);
    cp16(gA + 64 * NN, dA + 64 * 32);
    cp16(gB, dB);
    cp16(gB + 64 * NN, dB + 64 * 32);
    gA += 32; gB += 32;
    __syncthreads();
    bf16x8 af[4], bf[4];
#pragma unroll
    for (int i = 0; i < 4; i++) af[i] = *(const bf16x8*)(pa0 + i * 16 * 32);
#pragma unroll
    for (int j = 0; j < 4; j++) bf[j] = *(const bf16x8*)(pb0 + j * 16 * 32);
#pragma unroll
    for (int i = 0; i < 4; i++)
#pragma unroll
      for (int j = 0; j < 4; j++)
        acc[i][j] = __builtin_amdgcn_mfma_f32_16x16x32_bf16(af[i], bf[j], acc[i][j], 0, 0, 0);
    __syncthreads();
  }
  int quad4 = quad * 4;
  int colb = tn * 128 + wc * 64 + (lane & 15);
#pragma unroll
  for (int i = 0; i < 4; i++) {
#pragma unroll
    for (int j = 0; j < 4; j++) {
      int col = colb + j * 16;
      float bias = bb[col];
#pragma unroll
      for (int rg = 0; rg < 4; rg++) {
        int row = tm * 128 + wr * 64 + i * 16 + quad4 + rg;
        float v = acc[i][j][rg] + bias;
        float sg = 1.0f / (1.0f + __expf(-v));
        C[(size_t)row * 2048 + col] = f2bf(sg - 0.5f);
      }
    }
  }
}

// ---------------- column bias: kb = 0.5*sum_i k'[row,i] + mask (1 wave/row) ---
__global__ __launch_bounds__(256) void kbias_kernel(const u16* __restrict__ C,
                                                    const float* __restrict__ mask,
                                                    float* __restrict__ kb) {
  int w = threadIdx.x >> 6, lane = threadIdx.x & 63;
  int row = blockIdx.x * 4 + w;
  const ushort4* src = (const ushort4*)(C + (size_t)row * 2048 + 1024);
  float s = 0.f;
#pragma unroll
  for (int u = 0; u < 4; u++) {
    ushort4 v = src[lane + u * 64];
    s += (bf2f(v.x) + bf2f(v.y)) + (bf2f(v.z) + bf2f(v.w));
  }
#pragma unroll
  for (int off = 1; off < 64; off <<= 1) s += __shfl_xor(s, off);
  if (lane == 0) kb[row] = 0.5f * s + mask[row];
}

// ---------------- flash: one 128q x 128k tile per block; per-wave 64-key strip -
__global__ __launch_bounds__(256, 3) void flash_kernel(const u16* __restrict__ C,
                                                       const float* __restrict__ kb,
                                                       const float* __restrict__ r,
                                                       float* __restrict__ pm,
                                                       float* __restrict__ pl,
                                                       float* __restrict__ pt) {
  __shared__ u16 lA[128 * 32];
  __shared__ u16 lB[128 * 32];
  int bid = blockIdx.x;           // 8 * 16 * 16 = 2048
  int kc = bid & 15;
  int qt = (bid >> 4) & 15;
  int b  = bid >> 8;
  int tid = threadIdx.x;
  int w = tid >> 6, lane = tid & 63;
  int wr = w >> 1, wc = w & 1;
  int srow = tid >> 2;
  int scol = (tid & 3) * 8;
  int key0 = kc * 128;
  const u16* gA = C + (size_t)(b * SS + qt * 128 + srow) * 2048 + scol;
  const u16* gB = C + (size_t)(b * SS + key0 + srow) * 2048 + 1024 + scol;
  u16* dA = &lA[srow * 32 + scol];
  u16* dB = &lB[srow * 32 + scol];
  int quad = lane >> 4;
  const u16* pa0 = &lA[(wr * 64 + (lane & 15)) * 32 + quad * 8];
  const u16* pb0 = &lB[(wc * 64 + (lane & 15)) * 32 + quad * 8];

  f32x4 acc[4][4] = {};
  for (int kk = 0; kk < NN; kk += 32) {
    cp16(gA, dA);
    cp16(gA + 64 * 2048, dA + 64 * 32);
    cp16(gB, dB);
    cp16(gB + 64 * 2048, dB + 64 * 32);
    gA += 32; gB += 32;
    __syncthreads();
    bf16x8 af[4], bf[4];
#pragma unroll
    for (int i = 0; i < 4; i++) af[i] = *(const bf16x8*)(pa0 + i * 16 * 32);
#pragma unroll
    for (int j = 0; j < 4; j++) bf[j] = *(const bf16x8*)(pb0 + j * 16 * 32);
#pragma unroll
    for (int i = 0; i < 4; i++)
#pragma unroll
      for (int j = 0; j < 4; j++)
        acc[i][j] = __builtin_amdgcn_mfma_f32_16x16x32_bf16(af[i], bf[j], acc[i][j], 0, 0, 0);
    __syncthreads();
  }

  // epilogue: per-row softmax partial over this wave's 64-key strip
  float kbv[4], rv[4];
  int colg = b * SS + key0 + wc * 64 + (lane & 15);
#pragma unroll
  for (int j = 0; j < 4; j++) { kbv[j] = kb[colg + j * 16]; rv[j] = r[colg + j * 16]; }
  int quad4 = quad * 4;
  int chunk = kc * 2 + wc;
#pragma unroll
  for (int i = 0; i < 4; i++) {
#pragma unroll
    for (int rg = 0; rg < 4; rg++) {
      float lg[4];
      float tmax = -1e30f;
#pragma unroll
      for (int j = 0; j < 4; j++) { lg[j] = acc[i][j][rg] + kbv[j]; tmax = fmaxf(tmax, lg[j]); }
#pragma unroll
      for (int off = 1; off < 16; off <<= 1) tmax = fmaxf(tmax, __shfl_xor(tmax, off));
      float rs = 0.f, rt = 0.f;
#pragma unroll
      for (int j = 0; j < 4; j++) {
        float p = __expf(lg[j] - tmax);
        rs += p; rt += p * rv[j];
      }
#pragma unroll
      for (int off = 1; off < 16; off <<= 1) { rs += __shfl_xor(rs, off); rt += __shfl_xor(rt, off); }
      if ((lane & 15) == 0) {
        int grow = b * SS + qt * 128 + wr * 64 + i * 16 + quad4 + rg;
        pm[grow * NPC + chunk] = tmax;
        pl[grow * NPC + chunk] = rs;
        pt[grow * NPC + chunk] = rt;
      }
    }
  }
}

// ---------------- combine key-chunk partials ----------------
__global__ __launch_bounds__(256) void fixup_kernel(const float* __restrict__ pm,
                                                    const float* __restrict__ pl,
                                                    const float* __restrict__ pt,
                                                    float* __restrict__ out) {
  int row = blockIdx.x * 256 + threadIdx.x;
  float Mx = -1e30f;
#pragma unroll
  for (int c = 0; c < NPC; c++) Mx = fmaxf(Mx, pm[row * NPC + c]);
  float L = 0.f, T = 0.f;
#pragma unroll
  for (int c = 0; c < NPC; c++) {
    float a = __expf(pm[row * NPC + c] - Mx);
    L += pl[row * NPC + c] * a;
    T += pt[row * NPC + c] * a;
  }
  out[row] = T / L;
}

extern "C" void kernel_launch(void* const* d_in, const int* in_sizes, int n_in,
                              void* d_out, int out_size, void* d_ws, size_t ws_size,
                              hipStream_t stream) {
  const float* outer = (const float*)d_in[0];
  const float* mask  = (const float*)d_in[1];
  const float* Wk    = (const float*)d_in[2];
  const float* bk    = (const float*)d_in[3];
  const float* Wq    = (const float*)d_in[4];
  const float* bq    = (const float*)d_in[5];
  float* out = (float*)d_out;

  char* ws = (char*)d_ws;
  size_t off = 0;
  auto alloc = [&](size_t bytes) -> void* {
    void* p = ws + off;
    off = (off + bytes + 255) & ~(size_t)255;
    return p;
  };
  u16* Xb  = (u16*)alloc((size_t)MT * NN * 2);       // 32 MB bf16 outer
  u16* Wb  = (u16*)alloc((size_t)2048 * NN * 2);     // 4 MB bf16 [Wq;Wk]
  u16* Cq  = (u16*)alloc((size_t)MT * 2048 * 2);     // 64 MB bf16 [q'|k']
  float* bb = (float*)alloc(2048 * 4);
  float* rr = (float*)alloc((size_t)MT * 4);
  float* kb = (float*)alloc((size_t)MT * 4);
  float* pm = (float*)alloc((size_t)MT * NPC * 4);
  float* pl = (float*)alloc((size_t)MT * NPC * 4);
  float* pt = (float*)alloc((size_t)MT * NPC * 4);

  prep_x_kernel<<<dim3(MT / 4), dim3(256), 0, stream>>>(outer, Xb, rr);
  prep_w_kernel<<<dim3(2048), dim3(256), 0, stream>>>(Wq, Wk, bq, bk, Wb, bb);
  gemm1_kernel<<<dim3(16, 128), dim3(256), 0, stream>>>(Xb, Wb, bb, Cq);
  kbias_kernel<<<dim3(MT / 4), dim3(256), 0, stream>>>(Cq, mask, kb);
  flash_kernel<<<dim3(8 * 16 * NKC), dim3(256), 0, stream>>>(Cq, kb, rr, pm, pl, pt);
  fixup_kernel<<<dim3(MT / 256), dim3(256), 0, stream>>>(pm, pl, pt, out);
}

// Round 5
// 293.572 us; speedup vs baseline: 1.0475x; 1.0475x over previous
//
#include <hip/hip_runtime.h>
#include <hip/hip_bf16.h>

#define BB 8
#define SS 2048
#define NN 1024
#define MT (BB*SS)   // 16384
#define NKC 16       // key tiles of 128; each wave owns a 64-key strip -> 32 partials/row
#define NPC 32       // partial chunks per row (NKC * 2 wave-columns)

typedef __attribute__((ext_vector_type(8))) short bf16x8;
typedef __attribute__((ext_vector_type(4))) float f32x4;
typedef unsigned short u16;
typedef unsigned int u32;

__device__ __forceinline__ u16 f2bf(float f) {
  u32 u = __float_as_uint(f);
  u += 0x7fff + ((u >> 16) & 1);
  return (u16)(u >> 16);
}
__device__ __forceinline__ float bf2f(u16 h) {
  return __uint_as_float(((u32)h) << 16);
}

typedef __attribute__((address_space(1))) void GV;
typedef __attribute__((address_space(3))) void LV;
__device__ __forceinline__ void cp16(const void* g, void* l) {
  __builtin_amdgcn_global_load_lds((GV*)g, (LV*)l, 16, 0, 0);
}

// ------- prep: cast outer -> bf16, rowsum -> r, kb init = mask (1 wave/row) --
__global__ __launch_bounds__(256) void prep_x_kernel(const float* __restrict__ outer,
                                                     const float* __restrict__ mask,
                                                     u16* __restrict__ Xb,
                                                     float* __restrict__ r,
                                                     float* __restrict__ kb) {
  int w = threadIdx.x >> 6, lane = threadIdx.x & 63;
  int row = blockIdx.x * 4 + w;
  const float4* src = (const float4*)(outer + (size_t)row * NN);
  ushort4* dst = (ushort4*)(Xb + (size_t)row * NN);
  float s = 0.f;
#pragma unroll
  for (int u = 0; u < 4; u++) {
    int idx = lane + u * 64;
    float4 v = src[idx];
    ushort4 o;
    o.x = f2bf(v.x); o.y = f2bf(v.y); o.z = f2bf(v.z); o.w = f2bf(v.w);
    dst[idx] = o;
    s += (v.x + v.y) + (v.z + v.w);
  }
#pragma unroll
  for (int off = 1; off < 64; off <<= 1) s += __shfl_xor(s, off);
  if (lane == 0) { r[row] = s; kb[row] = mask[row]; }
}

// ---------------- prep: cast weights -> bf16 (rows 0..1023 = Wq, 1024.. = Wk) --
__global__ __launch_bounds__(256) void prep_w_kernel(const float* __restrict__ Wq,
                                                     const float* __restrict__ Wk,
                                                     const float* __restrict__ bq,
                                                     const float* __restrict__ bk,
                                                     u16* __restrict__ Wb,
                                                     float* __restrict__ bb) {
  int idx = blockIdx.x * 256 + threadIdx.x;   // 0 .. 524287 (x4 elems)
  int e = idx * 4;
  int rowm = e >> 10;
  int col = e & 1023;
  const float* srcp = (rowm < NN) ? (Wq + (size_t)rowm * NN + col)
                                  : (Wk + (size_t)(rowm - NN) * NN + col);
  float4 v = *(const float4*)srcp;
  ushort4 o; o.x = f2bf(v.x); o.y = f2bf(v.y); o.z = f2bf(v.z); o.w = f2bf(v.w);
  *(ushort4*)(Wb + (size_t)e) = o;
  if (idx < 2 * NN) bb[idx] = (idx < NN) ? bq[idx] : bk[idx - NN];
}

// ---------------- stage 1 GEMM: C[row][m] = sigmoid(X.Wb^T + bb) - 0.5 (bf16) --
// BK=64 (two 32-wide LDS buffers between one barrier pair).
// 1D grid 2048: xcd = tn>>1 affinity; fused kb partial-sum (cols >= 1024).
__global__ __launch_bounds__(256, 3) void gemm1_kernel(const u16* __restrict__ X,
                                                       const u16* __restrict__ W,
                                                       const float* __restrict__ bb,
                                                       u16* __restrict__ C,
                                                       float* __restrict__ kb) {
  __shared__ u16 lA[2][128 * 32];
  __shared__ u16 lB[2][128 * 32];
  int bid = blockIdx.x;
  int tn = ((bid & 7) << 1) | ((bid >> 3) & 1);   // 0..15
  int tm = bid >> 4;                               // 0..127
  int tid = threadIdx.x;
  int w = tid >> 6, lane = tid & 63;
  int wr = w >> 1, wc = w & 1;
  int srow = tid >> 2;
  int scol = (tid & 3) * 8;
  const u16* gA = X + (size_t)(tm * 128 + srow) * NN + scol;
  const u16* gB = W + (size_t)(tn * 128 + srow) * NN + scol;
  u16* dA0 = &lA[0][srow * 32 + scol];
  u16* dA1 = &lA[1][srow * 32 + scol];
  u16* dB0 = &lB[0][srow * 32 + scol];
  u16* dB1 = &lB[1][srow * 32 + scol];
  int quad = lane >> 4;
  const u16* pa0 = &lA[0][(wr * 64 + (lane & 15)) * 32 + quad * 8];
  const u16* pb0 = &lB[0][(wc * 64 + (lane & 15)) * 32 + quad * 8];
  const u16* pa1 = pa0 + 128 * 32;
  const u16* pb1 = pb0 + 128 * 32;
  f32x4 acc[4][4] = {};
  for (int kk = 0; kk < NN; kk += 64) {
    cp16(gA, dA0);           cp16(gA + 64 * NN, dA0 + 64 * 32);
    cp16(gB, dB0);           cp16(gB + 64 * NN, dB0 + 64 * 32);
    cp16(gA + 32, dA1);      cp16(gA + 32 + 64 * NN, dA1 + 64 * 32);
    cp16(gB + 32, dB1);      cp16(gB + 32 + 64 * NN, dB1 + 64 * 32);
    gA += 64; gB += 64;
    __syncthreads();
    {
      bf16x8 af[4], bf[4];
#pragma unroll
      for (int i = 0; i < 4; i++) af[i] = *(const bf16x8*)(pa0 + i * 16 * 32);
#pragma unroll
      for (int j = 0; j < 4; j++) bf[j] = *(const bf16x8*)(pb0 + j * 16 * 32);
#pragma unroll
      for (int i = 0; i < 4; i++)
#pragma unroll
        for (int j = 0; j < 4; j++)
          acc[i][j] = __builtin_amdgcn_mfma_f32_16x16x32_bf16(af[i], bf[j], acc[i][j], 0, 0, 0);
    }
    {
      bf16x8 af[4], bf[4];
#pragma unroll
      for (int i = 0; i < 4; i++) af[i] = *(const bf16x8*)(pa1 + i * 16 * 32);
#pragma unroll
      for (int j = 0; j < 4; j++) bf[j] = *(const bf16x8*)(pb1 + j * 16 * 32);
#pragma unroll
      for (int i = 0; i < 4; i++)
#pragma unroll
        for (int j = 0; j < 4; j++)
          acc[i][j] = __builtin_amdgcn_mfma_f32_16x16x32_bf16(af[i], bf[j], acc[i][j], 0, 0, 0);
    }
    __syncthreads();
  }
  int quad4 = quad * 4;
  int colb = tn * 128 + wc * 64 + (lane & 15);
  bool khalf = (tn >= 8);
#pragma unroll
  for (int i = 0; i < 4; i++) {
    float rsum[4] = {0.f, 0.f, 0.f, 0.f};
#pragma unroll
    for (int j = 0; j < 4; j++) {
      int col = colb + j * 16;
      float bias = bb[col];
#pragma unroll
      for (int rg = 0; rg < 4; rg++) {
        int row = tm * 128 + wr * 64 + i * 16 + quad4 + rg;
        float v = acc[i][j][rg] + bias;
        float sg = 1.0f / (1.0f + __expf(-v));
        u16 h = f2bf(sg - 0.5f);
        C[(size_t)row * 2048 + col] = h;
        rsum[rg] += bf2f(h);   // rounded value, matches what flash's MFMA sees
      }
    }
    if (khalf) {
#pragma unroll
      for (int rg = 0; rg < 4; rg++) {
        float s = rsum[rg];
#pragma unroll
        for (int off = 1; off < 16; off <<= 1) s += __shfl_xor(s, off);
        if ((lane & 15) == 0) {
          int row = tm * 128 + wr * 64 + i * 16 + quad4 + rg;
          atomicAdd(&kb[row], 0.5f * s);
        }
      }
    }
  }
}

// ---------------- flash: one 128q x 128k tile per block; BK=64; XCD=batch ----
__global__ __launch_bounds__(256, 3) void flash_kernel(const u16* __restrict__ C,
                                                       const float* __restrict__ kb,
                                                       const float* __restrict__ r,
                                                       float* __restrict__ pm,
                                                       float* __restrict__ pl,
                                                       float* __restrict__ pt) {
  __shared__ u16 lA[2][128 * 32];
  __shared__ u16 lB[2][128 * 32];
  int bid = blockIdx.x;           // 2048
  int b  = bid & 7;               // XCD-affine: each XCD owns one batch's k' in L2
  int kc = (bid >> 3) & 15;       // inner: q-tile reused from L2
  int qt = bid >> 7;
  int tid = threadIdx.x;
  int w = tid >> 6, lane = tid & 63;
  int wr = w >> 1, wc = w & 1;
  int srow = tid >> 2;
  int scol = (tid & 3) * 8;
  int key0 = kc * 128;
  const u16* gA = C + (size_t)(b * SS + qt * 128 + srow) * 2048 + scol;
  const u16* gB = C + (size_t)(b * SS + key0 + srow) * 2048 + 1024 + scol;
  u16* dA0 = &lA[0][srow * 32 + scol];
  u16* dA1 = &lA[1][srow * 32 + scol];
  u16* dB0 = &lB[0][srow * 32 + scol];
  u16* dB1 = &lB[1][srow * 32 + scol];
  int quad = lane >> 4;
  const u16* pa0 = &lA[0][(wr * 64 + (lane & 15)) * 32 + quad * 8];
  const u16* pb0 = &lB[0][(wc * 64 + (lane & 15)) * 32 + quad * 8];
  const u16* pa1 = pa0 + 128 * 32;
  const u16* pb1 = pb0 + 128 * 32;

  f32x4 acc[4][4] = {};
  for (int kk = 0; kk < NN; kk += 64) {
    cp16(gA, dA0);           cp16(gA + 64 * 2048, dA0 + 64 * 32);
    cp16(gB, dB0);           cp16(gB + 64 * 2048, dB0 + 64 * 32);
    cp16(gA + 32, dA1);      cp16(gA + 32 + 64 * 2048, dA1 + 64 * 32);
    cp16(gB + 32, dB1);      cp16(gB + 32 + 64 * 2048, dB1 + 64 * 32);
    gA += 64; gB += 64;
    __syncthreads();
    {
      bf16x8 af[4], bf[4];
#pragma unroll
      for (int i = 0; i < 4; i++) af[i] = *(const bf16x8*)(pa0 + i * 16 * 32);
#pragma unroll
      for (int j = 0; j < 4; j++) bf[j] = *(const bf16x8*)(pb0 + j * 16 * 32);
#pragma unroll
      for (int i = 0; i < 4; i++)
#pragma unroll
        for (int j = 0; j < 4; j++)
          acc[i][j] = __builtin_amdgcn_mfma_f32_16x16x32_bf16(af[i], bf[j], acc[i][j], 0, 0, 0);
    }
    {
      bf16x8 af[4], bf[4];
#pragma unroll
      for (int i = 0; i < 4; i++) af[i] = *(const bf16x8*)(pa1 + i * 16 * 32);
#pragma unroll
      for (int j = 0; j < 4; j++) bf[j] = *(const bf16x8*)(pb1 + j * 16 * 32);
#pragma unroll
      for (int i = 0; i < 4; i++)
#pragma unroll
        for (int j = 0; j < 4; j++)
          acc[i][j] = __builtin_amdgcn_mfma_f32_16x16x32_bf16(af[i], bf[j], acc[i][j], 0, 0, 0);
    }
    __syncthreads();
  }

  // epilogue: per-row softmax partial over this wave's 64-key strip
  float kbv[4], rv[4];
  int colg = b * SS + key0 + wc * 64 + (lane & 15);
#pragma unroll
  for (int j = 0; j < 4; j++) { kbv[j] = kb[colg + j * 16]; rv[j] = r[colg + j * 16]; }
  int quad4 = quad * 4;
  int chunk = kc * 2 + wc;
#pragma unroll
  for (int i = 0; i < 4; i++) {
#pragma unroll
    for (int rg = 0; rg < 4; rg++) {
      float lg[4];
      float tmax = -1e30f;
#pragma unroll
      for (int j = 0; j < 4; j++) { lg[j] = acc[i][j][rg] + kbv[j]; tmax = fmaxf(tmax, lg[j]); }
#pragma unroll
      for (int off = 1; off < 16; off <<= 1) tmax = fmaxf(tmax, __shfl_xor(tmax, off));
      float rs = 0.f, rt = 0.f;
#pragma unroll
      for (int j = 0; j < 4; j++) {
        float p = __expf(lg[j] - tmax);
        rs += p; rt += p * rv[j];
      }
#pragma unroll
      for (int off = 1; off < 16; off <<= 1) { rs += __shfl_xor(rs, off); rt += __shfl_xor(rt, off); }
      if ((lane & 15) == 0) {
        int grow = b * SS + qt * 128 + wr * 64 + i * 16 + quad4 + rg;
        pm[grow * NPC + chunk] = tmax;
        pl[grow * NPC + chunk] = rs;
        pt[grow * NPC + chunk] = rt;
      }
    }
  }
}

// ---------------- combine key-chunk partials ----------------
__global__ __launch_bounds__(256) void fixup_kernel(const float* __restrict__ pm,
                                                    const float* __restrict__ pl,
                                                    const float* __restrict__ pt,
                                                    float* __restrict__ out) {
  int row = blockIdx.x * 256 + threadIdx.x;
  float Mx = -1e30f;
#pragma unroll
  for (int c = 0; c < NPC; c++) Mx = fmaxf(Mx, pm[row * NPC + c]);
  float L = 0.f, T = 0.f;
#pragma unroll
  for (int c = 0; c < NPC; c++) {
    float a = __expf(pm[row * NPC + c] - Mx);
    L += pl[row * NPC + c] * a;
    T += pt[row * NPC + c] * a;
  }
  out[row] = T / L;
}

extern "C" void kernel_launch(void* const* d_in, const int* in_sizes, int n_in,
                              void* d_out, int out_size, void* d_ws, size_t ws_size,
                              hipStream_t stream) {
  const float* outer = (const float*)d_in[0];
  const float* mask  = (const float*)d_in[1];
  const float* Wk    = (const float*)d_in[2];
  const float* bk    = (const float*)d_in[3];
  const float* Wq    = (const float*)d_in[4];
  const float* bq    = (const float*)d_in[5];
  float* out = (float*)d_out;

  char* ws = (char*)d_ws;
  size_t off = 0;
  auto alloc = [&](size_t bytes) -> void* {
    void* p = ws + off;
    off = (off + bytes + 255) & ~(size_t)255;
    return p;
  };
  u16* Xb  = (u16*)alloc((size_t)MT * NN * 2);       // 32 MB bf16 outer
  u16* Wb  = (u16*)alloc((size_t)2048 * NN * 2);     // 4 MB bf16 [Wq;Wk]
  u16* Cq  = (u16*)alloc((size_t)MT * 2048 * 2);     // 64 MB bf16 [q'|k']
  float* bb = (float*)alloc(2048 * 4);
  float* rr = (float*)alloc((size_t)MT * 4);
  float* kb = (float*)alloc((size_t)MT * 4);
  float* pm = (float*)alloc((size_t)MT * NPC * 4);
  float* pl = (float*)alloc((size_t)MT * NPC * 4);
  float* pt = (float*)alloc((size_t)MT * NPC * 4);

  prep_x_kernel<<<dim3(MT / 4), dim3(256), 0, stream>>>(outer, mask, Xb, rr, kb);
  prep_w_kernel<<<dim3(2048), dim3(256), 0, stream>>>(Wq, Wk, bq, bk, Wb, bb);
  gemm1_kernel<<<dim3(2048), dim3(256), 0, stream>>>(Xb, Wb, bb, Cq, kb);
  flash_kernel<<<dim3(2048), dim3(256), 0, stream>>>(Cq, kb, rr, pm, pl, pt);
  fixup_kernel<<<dim3(MT / 256), dim3(256), 0, stream>>>(pm, pl, pt, out);
}